// Round 8
// baseline (195.107 us; speedup 1.0000x reference)
//
#include <hip/hip_runtime.h>

#define D_MODEL 2048
#define QKVC 2304
#define DH 128
#define NH 16
#define BATCH 2
#define SEQ 2048
#define MROWS (BATCH*SEQ)   // 4096

typedef __attribute__((ext_vector_type(4))) float f32x4;
typedef __attribute__((ext_vector_type(16))) float f32x16;
typedef __attribute__((ext_vector_type(8))) short s16x8;
typedef __attribute__((ext_vector_type(8))) __bf16 bf16x8;
typedef __attribute__((ext_vector_type(4))) unsigned int u32x4;

static __device__ __forceinline__ unsigned short f2bf(float f) {
  unsigned int u = __builtin_bit_cast(unsigned int, f);
  u += 0x7fff + ((u >> 16) & 1);   // round-to-nearest-even
  return (unsigned short)(u >> 16);
}

static __device__ __forceinline__ unsigned int pkbf(float a, float b) {
  unsigned short x = __builtin_bit_cast(unsigned short, (__bf16)a);
  unsigned short y = __builtin_bit_cast(unsigned short, (__bf16)b);
  return (unsigned int)x | ((unsigned int)y << 16);
}

static __device__ __forceinline__ f32x4 mfma16(s16x8 a, s16x8 b, f32x4 c) {
  return __builtin_amdgcn_mfma_f32_16x16x32_bf16(
      __builtin_bit_cast(bf16x8, a), __builtin_bit_cast(bf16x8, b), c, 0, 0, 0);
}

static __device__ __forceinline__ f32x16 mfma32(s16x8 a, s16x8 b, f32x16 c) {
  return __builtin_amdgcn_mfma_f32_32x32x16_bf16(
      __builtin_bit_cast(bf16x8, a), __builtin_bit_cast(bf16x8, b), c, 0, 0, 0);
}

typedef const __attribute__((address_space(1))) void gvoid_t;
typedef __attribute__((address_space(3))) void svoid_t;

static __device__ __forceinline__ void gload_lds16(const void* g, void* l) {
  __builtin_amdgcn_global_load_lds((gvoid_t*)g, (svoid_t*)l, 16, 0, 0);
}

// ---------------- fp32 -> bf16 elementwise (x) ----------------
__global__ void cvt_bf16_kernel(const float* __restrict__ in,
                                unsigned short* __restrict__ out, int n4) {
  int i = blockIdx.x * blockDim.x + threadIdx.x;
  int stride = gridDim.x * blockDim.x;
  for (int idx = i; idx < n4; idx += stride) {
    float4 v = ((const float4*)in)[idx];
    ushort4 o;
    o.x = f2bf(v.x); o.y = f2bf(v.y); o.z = f2bf(v.z); o.w = f2bf(v.w);
    ((ushort4*)out)[idx] = o;
  }
}

// ------------- transpose+convert: f32 [R][C] -> bf16 [C][R] -------------
__global__ void transpose_cvt_kernel(const float* __restrict__ in,
                                     unsigned short* __restrict__ out,
                                     int R, int C) {
  __shared__ float tile[32][33];
  int c0 = blockIdx.x * 32, r0 = blockIdx.y * 32;
  int tx = threadIdx.x, ty = threadIdx.y;
#pragma unroll
  for (int i = 0; i < 4; ++i)
    tile[ty + i*8][tx] = in[(size_t)(r0 + ty + i*8) * C + c0 + tx];
  __syncthreads();
#pragma unroll
  for (int i = 0; i < 4; ++i)
    out[(size_t)(c0 + ty + i*8) * R + r0 + tx] = f2bf(tile[tx][ty + i*8]);
}

// ------------- transpose V: VT[b][d][s] = qkv[b*S+s][2176+d] -------------
__global__ void transpose_v_kernel(const unsigned short* __restrict__ qkv,
                                   unsigned short* __restrict__ VT) {
  __shared__ unsigned short tile[32][33];
  int s0 = blockIdx.x * 32, d0 = blockIdx.y * 32, b = blockIdx.z;
  int tx = threadIdx.x, ty = threadIdx.y;
#pragma unroll
  for (int i = 0; i < 4; ++i)
    tile[ty + i*8][tx] =
        qkv[(size_t)(b*SEQ + s0 + ty + i*8) * QKVC + (D_MODEL + DH) + d0 + tx];
  __syncthreads();
#pragma unroll
  for (int i = 0; i < 4; ++i)
    VT[(size_t)(b*DH + d0 + ty + i*8) * SEQ + s0 + tx] = tile[tx][ty + i*8];
}

// ------------- GEMM: C[M,N] = A[M,K](bf16) * BT[N,K]^T(bf16) + bias -------------
template<int OUT_F32>
__global__ __launch_bounds__(256, 2)
void gemm_bt_kernel(const unsigned short* __restrict__ A,
                    const unsigned short* __restrict__ BT,
                    const float* __restrict__ bias,
                    void* __restrict__ Cout,
                    int M, int N, int K) {
  __shared__ unsigned short Al[128*32];
  __shared__ unsigned short Bl[128*32];
  int tid = threadIdx.x;
  int lane = tid & 63, wave = tid >> 6;
  int m0 = blockIdx.y * 128, n0 = blockIdx.x * 128;
  int wr = wave >> 1, wc = wave & 1;
  int fr = lane & 15, fq = lane >> 4;
  f32x4 acc[4][4] = {};

  int c0 = wave * 2;
  int kcol = (lane & 3) * 8;
  int rsub = (lane >> 2);

  for (int k0 = 0; k0 < K; k0 += 32) {
#pragma unroll
    for (int i = 0; i < 2; ++i) {
      int c = c0 + i;
      int row = c*16 + rsub;
      gload_lds16(A  + (size_t)(m0 + row)*K + k0 + kcol, (char*)Al + c*1024);
      gload_lds16(BT + (size_t)(n0 + row)*K + k0 + kcol, (char*)Bl + c*1024);
    }
    __syncthreads();
    s16x8 af[4], bfr[4];
#pragma unroll
    for (int m = 0; m < 4; ++m)
      af[m] = *(const s16x8*)&Al[(wr*64 + m*16 + fr)*32 + fq*8];
#pragma unroll
    for (int n = 0; n < 4; ++n)
      bfr[n] = *(const s16x8*)&Bl[(wc*64 + n*16 + fr)*32 + fq*8];
#pragma unroll
    for (int m = 0; m < 4; ++m)
#pragma unroll
      for (int n = 0; n < 4; ++n)
        acc[m][n] = mfma16(af[m], bfr[n], acc[m][n]);
    __syncthreads();
  }

#pragma unroll
  for (int n = 0; n < 4; ++n) {
    int col = n0 + wc*64 + n*16 + fr;
    float bv = bias[col];
#pragma unroll
    for (int m = 0; m < 4; ++m) {
      int rowb = m0 + wr*64 + m*16 + fq*4;
#pragma unroll
      for (int j = 0; j < 4; ++j) {
        float v = acc[m][n][j] + bv;
        if (OUT_F32) ((float*)Cout)[(size_t)(rowb + j)*N + col] = v;
        else ((unsigned short*)Cout)[(size_t)(rowb + j)*N + col] = f2bf(v);
      }
    }
  }
}

// ------------- causal MQA attention: uniform split-kv blocks -------------
// 256 blocks (1/CU), 512 threads = 8 waves = 2 groups of 4 (one head each).
// Block u: b = u>>7, hg = (u>>5)&3, x = u&31; qt_A = 63-x (long), qt_B = x.
// nkbA + nkbB = 33 for all x. Group 0: qt_A kv-blocks [0,17).
// Group 1: qt_B fully (nkbB blocks), then qt_A kv-blocks [17, nkbA) (16 total).
// Every block: exactly 17/16 steps -> identical duration, 2 waves/SIMD
// throughout, zero tail. qt_A halves merged intra-block via LDS partials.
__global__ __launch_bounds__(512, 2)
void mqa_attn_kernel(const unsigned short* __restrict__ qkv,
                     const unsigned short* __restrict__ VT,
                     unsigned short* __restrict__ O) {
  __shared__ unsigned short Kst[2][2][64*128];   // [stream][buf] 64 KB
  __shared__ unsigned short Vst[2][2][128*64];   // [stream][buf] 64 KB
  int u = blockIdx.x;                   // 0..255
  int b = u >> 7;
  int hg = (u >> 5) & 3;
  int x = u & 31;
  int qtA = 63 - x, qtB = x;
  int nkbA = (qtA >> 1) + 1, nkbB = (qtB >> 1) + 1;   // sum = 33
  const int G1 = 17;
  bool hasPart = (nkbA > G1);

  int tid = threadIdx.x;                // 0..511
  int grp = tid >> 8;                   // group / stream
  int tg  = tid & 255;                  // thread within group
  int lane = tid & 63;
  int wid4 = (tid >> 6) & 3;            // wave within group = head idx
  int fr = lane & 31, hi = lane >> 5;
  int h = hg*4 + wid4;
  const float C = 0.12751688f;          // (1/sqrt(128)) * log2(e)

  // which tile does group g work on at step st? (block-uniform per group)
  auto tile_desc = [&](int g, int st, int& qt, int& kb) -> bool {
    if (g == 0) { qt = qtA; kb = st; return st < G1; }
    if (st < nkbB) { qt = qtB; kb = st; return true; }
    int k2 = G1 + (st - nkbB);
    qt = qtA; kb = k2;
    return k2 < nkbA;
  };

#define STAGE_G(kv0_, Kp_, Vp_) do {                                        \
    _Pragma("unroll")                                                       \
    for (int i_ = 0; i_ < 4; ++i_) {                                        \
      int idx_ = i_*256 + tg;                                               \
      int r_ = idx_ >> 4, c_ = idx_ & 15;                                   \
      gload_lds16(qkv + (size_t)(b*SEQ + (kv0_) + r_)*QKVC + D_MODEL        \
                      + ((c_ ^ (r_ & 15)) * 8),                             \
                  (char*)(Kp_) + (size_t)idx_*16);                          \
      int d_ = idx_ >> 3, c2_ = idx_ & 7;                                   \
      gload_lds16(VT + (size_t)(b*DH + d_)*SEQ + (kv0_) + ((c2_^(d_&7))*8), \
                  (char*)(Vp_) + (size_t)idx_*16);                          \
    }                                                                       \
  } while (0)

  s16x8 qf[8];
  f32x16 oacc[4];
  float m_r, l_r;

  auto load_q = [&](int qt_) {
    const unsigned short* qb =
        qkv + (size_t)(b*SEQ + qt_*32 + fr)*QKVC + h*DH + hi*8;
#pragma unroll
    for (int s = 0; s < 8; ++s) qf[s] = *(const s16x8*)(qb + s*16);
  };
  auto reset_state = [&]() {
#pragma unroll
    for (int n2 = 0; n2 < 4; ++n2)
#pragma unroll
      for (int e = 0; e < 16; ++e) oacc[n2][e] = 0.f;
    m_r = -1.0e30f; l_r = 0.f;
  };

  auto do_tile = [&](const unsigned short* Kb, const unsigned short* Vb,
                     int q0, int kv0) {
    // QK^T (swapped): sfr[t] = S^T tile, D[row=kv][col=q]
    f32x16 sfr[2] = {};
    __builtin_amdgcn_s_setprio(1);
#pragma unroll
    for (int t = 0; t < 2; ++t) {
      int row = t*32 + fr;
#pragma unroll
      for (int s = 0; s < 8; ++s) {
        int cc = (s*2 + hi) ^ (fr & 15);
        s16x8 kf = *(const s16x8*)&Kb[row*128 + cc*8];
        sfr[t] = mfma32(kf, qf[s], sfr[t]);
      }
    }
    __builtin_amdgcn_s_setprio(0);

    // causal mask (raw-score domain) when tile crosses the diagonal
    if (kv0 + 63 > q0) {
      int q = q0 + fr;
#pragma unroll
      for (int t = 0; t < 2; ++t)
#pragma unroll
        for (int r = 0; r < 16; ++r) {
          int kv = kv0 + t*32 + (r & 3) + 8*(r >> 2) + 4*hi;
          if (kv > q) sfr[t][r] = -1.0e30f;
        }
    }

    // online softmax (folded scale*log2e, tree reductions, defer-max)
    float mx[8];
#pragma unroll
    for (int r = 0; r < 8; ++r)
      mx[r] = fmaxf(fmaxf(sfr[0][r], sfr[0][r+8]),
                    fmaxf(sfr[1][r], sfr[1][r+8]));
    float pm = fmaxf(fmaxf(fmaxf(mx[0], mx[4]), fmaxf(mx[1], mx[5])),
                     fmaxf(fmaxf(mx[2], mx[6]), fmaxf(mx[3], mx[7])));
    pm = fmaxf(pm, __shfl_xor(pm, 32));

    bool stable = __all(pm - m_r <= 90.0f) != 0;
    float fac = 1.0f;
    if (!stable) {
      float mnew = fmaxf(m_r, pm);
      fac = exp2f((m_r - mnew) * C);
      m_r = mnew;
    }
    float mC = m_r * C;
#pragma unroll
    for (int t = 0; t < 2; ++t)
#pragma unroll
      for (int r = 0; r < 16; ++r)
        sfr[t][r] = exp2f(__builtin_fmaf(sfr[t][r], C, -mC));

    float sm[8];
#pragma unroll
    for (int r = 0; r < 8; ++r)
      sm[r] = (sfr[0][r] + sfr[0][r+8]) + (sfr[1][r] + sfr[1][r+8]);
    float rs = ((sm[0]+sm[1]) + (sm[2]+sm[3]))
             + ((sm[4]+sm[5]) + (sm[6]+sm[7]));
    rs += __shfl_xor(rs, 32);
    l_r = l_r * fac + rs;

    if (!stable) {
#pragma unroll
      for (int r = 0; r < 16; ++r) {
        int src = (r & 3) + 8*(r >> 2) + 4*hi;
        float fv = __shfl(fac, src);
#pragma unroll
        for (int n2 = 0; n2 < 4; ++n2) oacc[n2][r] *= fv;
      }
    }

    // P -> A-fragments in-register (pack + shfl_xor 32) + PV
#pragma unroll
    for (int t = 0; t < 2; ++t) {
      s16x8 pa[2];
#pragma unroll
      for (int ks = 0; ks < 2; ++ks) {
        unsigned int X0 = pkbf(sfr[t][8*ks+0], sfr[t][8*ks+1]);
        unsigned int X1 = pkbf(sfr[t][8*ks+2], sfr[t][8*ks+3]);
        unsigned int Y0 = pkbf(sfr[t][8*ks+4], sfr[t][8*ks+5]);
        unsigned int Y1 = pkbf(sfr[t][8*ks+6], sfr[t][8*ks+7]);
        unsigned int s0 = __shfl_xor(hi ? X0 : Y0, 32);
        unsigned int s1 = __shfl_xor(hi ? X1 : Y1, 32);
        u32x4 pw;
        pw[0] = hi ? s0 : X0;
        pw[1] = hi ? s1 : X1;
        pw[2] = hi ? Y0 : s0;
        pw[3] = hi ? Y1 : s1;
        pa[ks] = __builtin_bit_cast(s16x8, pw);
      }
      __builtin_amdgcn_s_setprio(1);
#pragma unroll
      for (int n2 = 0; n2 < 4; ++n2) {
        int d = n2*32 + fr;
#pragma unroll
        for (int ks = 0; ks < 2; ++ks) {
          int cc = (t*4 + ks*2 + hi) ^ (d & 7);
          s16x8 vf = *(const s16x8*)&Vb[d*64 + cc*8];
          oacc[n2] = mfma32(pa[ks], vf, oacc[n2]);
        }
      }
      __builtin_amdgcn_s_setprio(0);
    }
  };

  auto do_epilogue = [&](int qt_) {
    float invl = 1.0f / l_r;
#pragma unroll
    for (int r = 0; r < 16; ++r) {
      int qrow = (r & 3) + 8*(r >> 2) + 4*hi;
      float iv = __shfl(invl, qrow);
      size_t rowoff = (size_t)(b*SEQ + qt_*32 + qrow)*D_MODEL + h*DH;
#pragma unroll
      for (int n2 = 0; n2 < 4; ++n2)
        O[rowoff + n2*32 + fr] = f2bf(oacc[n2][r] * iv);
    }
  };

  // ---- init ----
  load_q(grp ? qtB : qtA);
  reset_state();

  // ---- prologue: stage T(0) for my stream ----
  {
    int qts, kbs;
    tile_desc(grp, 0, qts, kbs);
    STAGE_G(kbs*64, &Kst[grp][0][0], &Vst[grp][0][0]);
  }
  __syncthreads();

  // ---- main loop: 17 lockstep steps ----
  for (int st = 0; st < G1; ++st) {
    int qtn, kbn;
    if (tile_desc(grp, st + 1, qtn, kbn))
      STAGE_G(kbn*64, &Kst[grp][(st+1)&1][0], &Vst[grp][(st+1)&1][0]);

    int qtc, kbc;
    if (tile_desc(grp, st, qtc, kbc)) {
      do_tile(&Kst[grp][st&1][0], &Vst[grp][st&1][0], qtc*32, kbc*64);
      if (grp == 1 && st == nkbB - 1) {
        do_epilogue(qtB);       // qt_B complete -> write it out
        load_q(qtA);            // switch to qt_A upper kv range
        reset_state();
      }
    }
    __syncthreads();
  }

  // ---- merge qt_A halves ----
  if (grp == 1 && hasPart) {
    float* Dls = (float*)&Kst[0][0][0];     // 16K floats = 64 KB
    float* Mls = (float*)&Vst[0][0][0];
#pragma unroll
    for (int r = 0; r < 16; ++r) {
      int q = (r & 3) + 8*(r >> 2) + 4*hi;
#pragma unroll
      for (int n2 = 0; n2 < 4; ++n2)
        Dls[(wid4*32 + q)*128 + n2*32 + fr] = oacc[n2][r];
    }
    if (hi == 0) {
      Mls[wid4*32 + fr] = m_r;
      Mls[128 + wid4*32 + fr] = l_r;
    }
  }
  __syncthreads();

  if (grp == 0) {
    if (hasPart) {
      const float* Dls = (const float*)&Kst[0][0][0];
      const float* Mls = (const float*)&Vst[0][0][0];
      float m2 = Mls[wid4*32 + fr], l2 = Mls[128 + wid4*32 + fr];
      float mm = fmaxf(m_r, m2);
      float fA = exp2f((m_r - mm) * C);
      float fB = exp2f((m2 - mm) * C);
      float inv = 1.0f / (fA*l_r + fB*l2);
#pragma unroll
      for (int r = 0; r < 16; ++r) {
        int q = (r & 3) + 8*(r >> 2) + 4*hi;
        float fAs = __shfl(fA, q), fBs = __shfl(fB, q), invs = __shfl(inv, q);
        size_t rowoff = (size_t)(b*SEQ + qtA*32 + q)*D_MODEL + h*DH;
#pragma unroll
        for (int n2 = 0; n2 < 4; ++n2) {
          float o2 = Dls[(wid4*32 + q)*128 + n2*32 + fr];
          O[rowoff + n2*32 + fr] = f2bf((fAs*oacc[n2][r] + fBs*o2) * invs);
        }
      }
    } else {
      do_epilogue(qtA);
    }
  }
#undef STAGE_G
}

extern "C" void kernel_launch(void* const* d_in, const int* in_sizes, int n_in,
                              void* d_out, int out_size, void* d_ws, size_t ws_size,
                              hipStream_t stream) {
  const float* x     = (const float*)d_in[0];
  const float* W_qkv = (const float*)d_in[1];
  const float* b_qkv = (const float*)d_in[2];
  const float* W_out = (const float*)d_in[3];
  const float* b_out = (const float*)d_in[4];
  float* out = (float*)d_out;

  unsigned short* x_bf = (unsigned short*)d_ws;
  unsigned short* WqT  = x_bf + (size_t)MROWS * D_MODEL;
  unsigned short* WoT  = WqT  + (size_t)QKVC * D_MODEL;
  unsigned short* qkvb = WoT  + (size_t)D_MODEL * D_MODEL;
  unsigned short* VTb  = qkvb + (size_t)MROWS * QKVC;
  unsigned short* Ob   = VTb  + (size_t)BATCH * DH * SEQ;

  dim3 tb(32, 8);
  cvt_bf16_kernel<<<2048, 256, 0, stream>>>(x, x_bf, (MROWS * D_MODEL) / 4);
  transpose_cvt_kernel<<<dim3(QKVC/32, D_MODEL/32), tb, 0, stream>>>(W_qkv, WqT, D_MODEL, QKVC);
  transpose_cvt_kernel<<<dim3(D_MODEL/32, D_MODEL/32), tb, 0, stream>>>(W_out, WoT, D_MODEL, D_MODEL);

  gemm_bt_kernel<0><<<dim3(QKVC/128, MROWS/128), 256, 0, stream>>>(
      x_bf, WqT, b_qkv, qkvb, MROWS, QKVC, D_MODEL);

  transpose_v_kernel<<<dim3(SEQ/32, DH/32, BATCH), tb, 0, stream>>>(qkvb, VTb);

  mqa_attn_kernel<<<dim3(256), 512, 0, stream>>>(qkvb, VTb, Ob);

  gemm_bt_kernel<1><<<dim3(D_MODEL/128, MROWS/128), 256, 0, stream>>>(
      Ob, WoT, b_out, out, MROWS, D_MODEL, D_MODEL);
}

// Round 9
// 194.885 us; speedup vs baseline: 1.0011x; 1.0011x over previous
//
#include <hip/hip_runtime.h>

#define D_MODEL 2048
#define QKVC 2304
#define DH 128
#define NH 16
#define BATCH 2
#define SEQ 2048
#define MROWS (BATCH*SEQ)   // 4096

typedef __attribute__((ext_vector_type(4))) float f32x4;
typedef __attribute__((ext_vector_type(16))) float f32x16;
typedef __attribute__((ext_vector_type(8))) short s16x8;
typedef __attribute__((ext_vector_type(8))) __bf16 bf16x8;
typedef __attribute__((ext_vector_type(4))) unsigned int u32x4;

static __device__ __forceinline__ unsigned short f2bf(float f) {
  unsigned int u = __builtin_bit_cast(unsigned int, f);
  u += 0x7fff + ((u >> 16) & 1);   // round-to-nearest-even
  return (unsigned short)(u >> 16);
}

static __device__ __forceinline__ unsigned int pkbf(float a, float b) {
  unsigned short x = __builtin_bit_cast(unsigned short, (__bf16)a);
  unsigned short y = __builtin_bit_cast(unsigned short, (__bf16)b);
  return (unsigned int)x | ((unsigned int)y << 16);
}

static __device__ __forceinline__ f32x4 mfma16(s16x8 a, s16x8 b, f32x4 c) {
  return __builtin_amdgcn_mfma_f32_16x16x32_bf16(
      __builtin_bit_cast(bf16x8, a), __builtin_bit_cast(bf16x8, b), c, 0, 0, 0);
}

static __device__ __forceinline__ f32x16 mfma32(s16x8 a, s16x8 b, f32x16 c) {
  return __builtin_amdgcn_mfma_f32_32x32x16_bf16(
      __builtin_bit_cast(bf16x8, a), __builtin_bit_cast(bf16x8, b), c, 0, 0, 0);
}

typedef const __attribute__((address_space(1))) void gvoid_t;
typedef __attribute__((address_space(3))) void svoid_t;

static __device__ __forceinline__ void gload_lds16(const void* g, void* l) {
  __builtin_amdgcn_global_load_lds((gvoid_t*)g, (svoid_t*)l, 16, 0, 0);
}

// ---------------- fp32 -> bf16 elementwise (x) ----------------
__global__ void cvt_bf16_kernel(const float* __restrict__ in,
                                unsigned short* __restrict__ out, int n4) {
  int i = blockIdx.x * blockDim.x + threadIdx.x;
  int stride = gridDim.x * blockDim.x;
  for (int idx = i; idx < n4; idx += stride) {
    float4 v = ((const float4*)in)[idx];
    ushort4 o;
    o.x = f2bf(v.x); o.y = f2bf(v.y); o.z = f2bf(v.z); o.w = f2bf(v.w);
    ((ushort4*)out)[idx] = o;
  }
}

// ------------- transpose+convert: f32 [R][C] -> bf16 [C][R] -------------
__global__ void transpose_cvt_kernel(const float* __restrict__ in,
                                     unsigned short* __restrict__ out,
                                     int R, int C) {
  __shared__ float tile[32][33];
  int c0 = blockIdx.x * 32, r0 = blockIdx.y * 32;
  int tx = threadIdx.x, ty = threadIdx.y;
#pragma unroll
  for (int i = 0; i < 4; ++i)
    tile[ty + i*8][tx] = in[(size_t)(r0 + ty + i*8) * C + c0 + tx];
  __syncthreads();
#pragma unroll
  for (int i = 0; i < 4; ++i)
    out[(size_t)(c0 + ty + i*8) * R + r0 + tx] = f2bf(tile[tx][ty + i*8]);
}

// ------------- transpose V: VT[b][d][s] = qkv[b*S+s][2176+d] -------------
__global__ void transpose_v_kernel(const unsigned short* __restrict__ qkv,
                                   unsigned short* __restrict__ VT) {
  __shared__ unsigned short tile[32][33];
  int s0 = blockIdx.x * 32, d0 = blockIdx.y * 32, b = blockIdx.z;
  int tx = threadIdx.x, ty = threadIdx.y;
#pragma unroll
  for (int i = 0; i < 4; ++i)
    tile[ty + i*8][tx] =
        qkv[(size_t)(b*SEQ + s0 + ty + i*8) * QKVC + (D_MODEL + DH) + d0 + tx];
  __syncthreads();
#pragma unroll
  for (int i = 0; i < 4; ++i)
    VT[(size_t)(b*DH + d0 + ty + i*8) * SEQ + s0 + tx] = tile[tx][ty + i*8];
}

// ------------- GEMM: C[M,N] = A[M,K](bf16) * BT[N,K]^T(bf16) + bias -------------
template<int OUT_F32>
__global__ __launch_bounds__(256, 2)
void gemm_bt_kernel(const unsigned short* __restrict__ A,
                    const unsigned short* __restrict__ BT,
                    const float* __restrict__ bias,
                    void* __restrict__ Cout,
                    int M, int N, int K) {
  __shared__ unsigned short Al[128*32];
  __shared__ unsigned short Bl[128*32];
  int tid = threadIdx.x;
  int lane = tid & 63, wave = tid >> 6;
  int m0 = blockIdx.y * 128, n0 = blockIdx.x * 128;
  int wr = wave >> 1, wc = wave & 1;
  int fr = lane & 15, fq = lane >> 4;
  f32x4 acc[4][4] = {};

  int c0 = wave * 2;
  int kcol = (lane & 3) * 8;
  int rsub = (lane >> 2);

  for (int k0 = 0; k0 < K; k0 += 32) {
#pragma unroll
    for (int i = 0; i < 2; ++i) {
      int c = c0 + i;
      int row = c*16 + rsub;
      gload_lds16(A  + (size_t)(m0 + row)*K + k0 + kcol, (char*)Al + c*1024);
      gload_lds16(BT + (size_t)(n0 + row)*K + k0 + kcol, (char*)Bl + c*1024);
    }
    __syncthreads();
    s16x8 af[4], bfr[4];
#pragma unroll
    for (int m = 0; m < 4; ++m)
      af[m] = *(const s16x8*)&Al[(wr*64 + m*16 + fr)*32 + fq*8];
#pragma unroll
    for (int n = 0; n < 4; ++n)
      bfr[n] = *(const s16x8*)&Bl[(wc*64 + n*16 + fr)*32 + fq*8];
#pragma unroll
    for (int m = 0; m < 4; ++m)
#pragma unroll
      for (int n = 0; n < 4; ++n)
        acc[m][n] = mfma16(af[m], bfr[n], acc[m][n]);
    __syncthreads();
  }

#pragma unroll
  for (int n = 0; n < 4; ++n) {
    int col = n0 + wc*64 + n*16 + fr;
    float bv = bias[col];
#pragma unroll
    for (int m = 0; m < 4; ++m) {
      int rowb = m0 + wr*64 + m*16 + fq*4;
#pragma unroll
      for (int j = 0; j < 4; ++j) {
        float v = acc[m][n][j] + bv;
        if (OUT_F32) ((float*)Cout)[(size_t)(rowb + j)*N + col] = v;
        else ((unsigned short*)Cout)[(size_t)(rowb + j)*N + col] = f2bf(v);
      }
    }
  }
}

// ------------- causal MQA attention: uniform split-kv blocks -------------
// 256 blocks (1/CU), 512 threads = 8 waves = 2 groups of 4 (one head each).
// Block u: b = u>>7, hg = (u>>5)&3, x = u&31; qt_A = 63-x (long), qt_B = x.
// nkbA + nkbB = 33 for all x. Group 0: qt_A kv-blocks [0,17).
// Group 1: qt_B fully (nkbB blocks), then qt_A kv-blocks [17, nkbA) (16 total).
// Every block: exactly 17/16 steps -> identical duration, 2 waves/SIMD
// throughout, zero tail. qt_A halves merged intra-block via LDS partials.
__global__ __launch_bounds__(512, 2)
void mqa_attn_kernel(const unsigned short* __restrict__ qkv,
                     const unsigned short* __restrict__ VT,
                     unsigned short* __restrict__ O) {
  __shared__ unsigned short Kst[2][2][64*128];   // [stream][buf] 64 KB
  __shared__ unsigned short Vst[2][2][128*64];   // [stream][buf] 64 KB
  int u = blockIdx.x;                   // 0..255
  int b = u >> 7;
  int hg = (u >> 5) & 3;
  int x = u & 31;
  int qtA = 63 - x, qtB = x;
  int nkbA = (qtA >> 1) + 1, nkbB = (qtB >> 1) + 1;   // sum = 33
  const int G1 = 17;
  bool hasPart = (nkbA > G1);

  int tid = threadIdx.x;                // 0..511
  int grp = tid >> 8;                   // group / stream
  int tg  = tid & 255;                  // thread within group
  int lane = tid & 63;
  int wid4 = (tid >> 6) & 3;            // wave within group = head idx
  int fr = lane & 31, hi = lane >> 5;
  int h = hg*4 + wid4;
  const float C = 0.12751688f;          // (1/sqrt(128)) * log2(e)

  // which tile does group g work on at step st? (block-uniform per group)
  auto tile_desc = [&](int g, int st, int& qt, int& kb) -> bool {
    if (g == 0) { qt = qtA; kb = st; return st < G1; }
    if (st < nkbB) { qt = qtB; kb = st; return true; }
    int k2 = G1 + (st - nkbB);
    qt = qtA; kb = k2;
    return k2 < nkbA;
  };

#define STAGE_G(kv0_, Kp_, Vp_) do {                                        \
    _Pragma("unroll")                                                       \
    for (int i_ = 0; i_ < 4; ++i_) {                                        \
      int idx_ = i_*256 + tg;                                               \
      int r_ = idx_ >> 4, c_ = idx_ & 15;                                   \
      gload_lds16(qkv + (size_t)(b*SEQ + (kv0_) + r_)*QKVC + D_MODEL        \
                      + ((c_ ^ (r_ & 15)) * 8),                             \
                  (char*)(Kp_) + (size_t)idx_*16);                          \
      int d_ = idx_ >> 3, c2_ = idx_ & 7;                                   \
      gload_lds16(VT + (size_t)(b*DH + d_)*SEQ + (kv0_) + ((c2_^(d_&7))*8), \
                  (char*)(Vp_) + (size_t)idx_*16);                          \
    }                                                                       \
  } while (0)

  s16x8 qf[8];
  f32x16 oacc[4];
  float m_r, l_r;

  auto load_q = [&](int qt_) {
    const unsigned short* qb =
        qkv + (size_t)(b*SEQ + qt_*32 + fr)*QKVC + h*DH + hi*8;
#pragma unroll
    for (int s = 0; s < 8; ++s) qf[s] = *(const s16x8*)(qb + s*16);
  };
  auto reset_state = [&]() {
#pragma unroll
    for (int n2 = 0; n2 < 4; ++n2)
#pragma unroll
      for (int e = 0; e < 16; ++e) oacc[n2][e] = 0.f;
    m_r = -1.0e30f; l_r = 0.f;
  };

  auto do_tile = [&](const unsigned short* Kb, const unsigned short* Vb,
                     int q0, int kv0) {
    // QK^T (swapped): sfr[t] = S^T tile, D[row=kv][col=q]
    f32x16 sfr[2] = {};
    __builtin_amdgcn_s_setprio(1);
#pragma unroll
    for (int t = 0; t < 2; ++t) {
      int row = t*32 + fr;
#pragma unroll
      for (int s = 0; s < 8; ++s) {
        int cc = (s*2 + hi) ^ (fr & 15);
        s16x8 kf = *(const s16x8*)&Kb[row*128 + cc*8];
        sfr[t] = mfma32(kf, qf[s], sfr[t]);
      }
    }
    __builtin_amdgcn_s_setprio(0);

    // causal mask (raw-score domain) when tile crosses the diagonal
    if (kv0 + 63 > q0) {
      int q = q0 + fr;
#pragma unroll
      for (int t = 0; t < 2; ++t)
#pragma unroll
        for (int r = 0; r < 16; ++r) {
          int kv = kv0 + t*32 + (r & 3) + 8*(r >> 2) + 4*hi;
          if (kv > q) sfr[t][r] = -1.0e30f;
        }
    }

    // online softmax (folded scale*log2e, tree reductions, defer-max)
    float mx[8];
#pragma unroll
    for (int r = 0; r < 8; ++r)
      mx[r] = fmaxf(fmaxf(sfr[0][r], sfr[0][r+8]),
                    fmaxf(sfr[1][r], sfr[1][r+8]));
    float pm = fmaxf(fmaxf(fmaxf(mx[0], mx[4]), fmaxf(mx[1], mx[5])),
                     fmaxf(fmaxf(mx[2], mx[6]), fmaxf(mx[3], mx[7])));
    pm = fmaxf(pm, __shfl_xor(pm, 32));

    bool stable = __all(pm - m_r <= 90.0f) != 0;
    float fac = 1.0f;
    if (!stable) {
      float mnew = fmaxf(m_r, pm);
      fac = exp2f((m_r - mnew) * C);
      m_r = mnew;
    }
    float mC = m_r * C;
#pragma unroll
    for (int t = 0; t < 2; ++t)
#pragma unroll
      for (int r = 0; r < 16; ++r)
        sfr[t][r] = exp2f(__builtin_fmaf(sfr[t][r], C, -mC));

    float sm[8];
#pragma unroll
    for (int r = 0; r < 8; ++r)
      sm[r] = (sfr[0][r] + sfr[0][r+8]) + (sfr[1][r] + sfr[1][r+8]);
    float rs = ((sm[0]+sm[1]) + (sm[2]+sm[3]))
             + ((sm[4]+sm[5]) + (sm[6]+sm[7]));
    rs += __shfl_xor(rs, 32);
    l_r = l_r * fac + rs;

    if (!stable) {
#pragma unroll
      for (int r = 0; r < 16; ++r) {
        int src = (r & 3) + 8*(r >> 2) + 4*hi;
        float fv = __shfl(fac, src);
#pragma unroll
        for (int n2 = 0; n2 < 4; ++n2) oacc[n2][r] *= fv;
      }
    }

    // P -> A-fragments in-register (pack + shfl_xor 32) + PV
#pragma unroll
    for (int t = 0; t < 2; ++t) {
      s16x8 pa[2];
#pragma unroll
      for (int ks = 0; ks < 2; ++ks) {
        unsigned int X0 = pkbf(sfr[t][8*ks+0], sfr[t][8*ks+1]);
        unsigned int X1 = pkbf(sfr[t][8*ks+2], sfr[t][8*ks+3]);
        unsigned int Y0 = pkbf(sfr[t][8*ks+4], sfr[t][8*ks+5]);
        unsigned int Y1 = pkbf(sfr[t][8*ks+6], sfr[t][8*ks+7]);
        unsigned int s0 = __shfl_xor(hi ? X0 : Y0, 32);
        unsigned int s1 = __shfl_xor(hi ? X1 : Y1, 32);
        u32x4 pw;
        pw[0] = hi ? s0 : X0;
        pw[1] = hi ? s1 : X1;
        pw[2] = hi ? Y0 : s0;
        pw[3] = hi ? Y1 : s1;
        pa[ks] = __builtin_bit_cast(s16x8, pw);
      }
      __builtin_amdgcn_s_setprio(1);
#pragma unroll
      for (int n2 = 0; n2 < 4; ++n2) {
        int d = n2*32 + fr;
#pragma unroll
        for (int ks = 0; ks < 2; ++ks) {
          int cc = (t*4 + ks*2 + hi) ^ (d & 7);
          s16x8 vf = *(const s16x8*)&Vb[d*64 + cc*8];
          oacc[n2] = mfma32(pa[ks], vf, oacc[n2]);
        }
      }
      __builtin_amdgcn_s_setprio(0);
    }
  };

  auto do_epilogue = [&](int qt_) {
    float invl = 1.0f / l_r;
#pragma unroll
    for (int r = 0; r < 16; ++r) {
      int qrow = (r & 3) + 8*(r >> 2) + 4*hi;
      float iv = __shfl(invl, qrow);
      size_t rowoff = (size_t)(b*SEQ + qt_*32 + qrow)*D_MODEL + h*DH;
#pragma unroll
      for (int n2 = 0; n2 < 4; ++n2)
        O[rowoff + n2*32 + fr] = f2bf(oacc[n2][r] * iv);
    }
  };

  // ---- init ----
  load_q(grp ? qtB : qtA);
  reset_state();

  // ---- prologue: stage T(0) for my stream ----
  {
    int qts, kbs;
    tile_desc(grp, 0, qts, kbs);
    STAGE_G(kbs*64, &Kst[grp][0][0], &Vst[grp][0][0]);
  }
  __syncthreads();

  // ---- main loop: 17 lockstep steps ----
  for (int st = 0; st < G1; ++st) {
    int qtn, kbn;
    if (tile_desc(grp, st + 1, qtn, kbn))
      STAGE_G(kbn*64, &Kst[grp][(st+1)&1][0], &Vst[grp][(st+1)&1][0]);

    int qtc, kbc;
    if (tile_desc(grp, st, qtc, kbc)) {
      do_tile(&Kst[grp][st&1][0], &Vst[grp][st&1][0], qtc*32, kbc*64);
      if (grp == 1 && st == nkbB - 1) {
        do_epilogue(qtB);       // qt_B complete -> write it out
        load_q(qtA);            // switch to qt_A upper kv range
        reset_state();
      }
    }
    __syncthreads();
  }

  // ---- merge qt_A halves ----
  if (grp == 1 && hasPart) {
    float* Dls = (float*)&Kst[0][0][0];     // 16K floats = 64 KB
    float* Mls = (float*)&Vst[0][0][0];
#pragma unroll
    for (int r = 0; r < 16; ++r) {
      int q = (r & 3) + 8*(r >> 2) + 4*hi;
#pragma unroll
      for (int n2 = 0; n2 < 4; ++n2)
        Dls[(wid4*32 + q)*128 + n2*32 + fr] = oacc[n2][r];
    }
    if (hi == 0) {
      Mls[wid4*32 + fr] = m_r;
      Mls[128 + wid4*32 + fr] = l_r;
    }
  }
  __syncthreads();

  if (grp == 0) {
    if (hasPart) {
      const float* Dls = (const float*)&Kst[0][0][0];
      const float* Mls = (const float*)&Vst[0][0][0];
      float m2 = Mls[wid4*32 + fr], l2 = Mls[128 + wid4*32 + fr];
      float mm = fmaxf(m_r, m2);
      float fA = exp2f((m_r - mm) * C);
      float fB = exp2f((m2 - mm) * C);
      float inv = 1.0f / (fA*l_r + fB*l2);
#pragma unroll
      for (int r = 0; r < 16; ++r) {
        int q = (r & 3) + 8*(r >> 2) + 4*hi;
        float fAs = __shfl(fA, q), fBs = __shfl(fB, q), invs = __shfl(inv, q);
        size_t rowoff = (size_t)(b*SEQ + qtA*32 + q)*D_MODEL + h*DH;
#pragma unroll
        for (int n2 = 0; n2 < 4; ++n2) {
          float o2 = Dls[(wid4*32 + q)*128 + n2*32 + fr];
          O[rowoff + n2*32 + fr] = f2bf((fAs*oacc[n2][r] + fBs*o2) * invs);
        }
      }
    } else {
      do_epilogue(qtA);
    }
  }
#undef STAGE_G
}

extern "C" void kernel_launch(void* const* d_in, const int* in_sizes, int n_in,
                              void* d_out, int out_size, void* d_ws, size_t ws_size,
                              hipStream_t stream) {
  const float* x     = (const float*)d_in[0];
  const float* W_qkv = (const float*)d_in[1];
  const float* b_qkv = (const float*)d_in[2];
  const float* W_out = (const float*)d_in[3];
  const float* b_out = (const float*)d_in[4];
  float* out = (float*)d_out;

  unsigned short* x_bf = (unsigned short*)d_ws;
  unsigned short* WqT  = x_bf + (size_t)MROWS * D_MODEL;
  unsigned short* WoT  = WqT  + (size_t)QKVC * D_MODEL;
  unsigned short* qkvb = WoT  + (size_t)D_MODEL * D_MODEL;
  unsigned short* VTb  = qkvb + (size_t)MROWS * QKVC;
  unsigned short* Ob   = VTb  + (size_t)BATCH * DH * SEQ;

  dim3 tb(32, 8);
  cvt_bf16_kernel<<<2048, 256, 0, stream>>>(x, x_bf, (MROWS * D_MODEL) / 4);
  transpose_cvt_kernel<<<dim3(QKVC/32, D_MODEL/32), tb, 0, stream>>>(W_qkv, WqT, D_MODEL, QKVC);
  transpose_cvt_kernel<<<dim3(D_MODEL/32, D_MODEL/32), tb, 0, stream>>>(W_out, WoT, D_MODEL, D_MODEL);

  gemm_bt_kernel<0><<<dim3(QKVC/128, MROWS/128), 256, 0, stream>>>(
      x_bf, WqT, b_qkv, qkvb, MROWS, QKVC, D_MODEL);

  transpose_v_kernel<<<dim3(SEQ/32, DH/32, BATCH), tb, 0, stream>>>(qkvb, VTb);

  mqa_attn_kernel<<<dim3(256), 512, 0, stream>>>(qkvb, VTb, Ob);

  gemm_bt_kernel<1><<<dim3(D_MODEL/128, MROWS/128), 256, 0, stream>>>(
      Ob, WoT, b_out, out, MROWS, D_MODEL, D_MODEL);
}

// Round 10
// 194.665 us; speedup vs baseline: 1.0023x; 1.0011x over previous
//
#include <hip/hip_runtime.h>

#define D_MODEL 2048
#define QKVC 2304
#define DH 128
#define NH 16
#define BATCH 2
#define SEQ 2048
#define MROWS (BATCH*SEQ)   // 4096

typedef __attribute__((ext_vector_type(4))) float f32x4;
typedef __attribute__((ext_vector_type(16))) float f32x16;
typedef __attribute__((ext_vector_type(8))) short s16x8;
typedef __attribute__((ext_vector_type(8))) __bf16 bf16x8;
typedef __attribute__((ext_vector_type(4))) unsigned int u32x4;

static __device__ __forceinline__ unsigned short f2bf(float f) {
  unsigned int u = __builtin_bit_cast(unsigned int, f);
  u += 0x7fff + ((u >> 16) & 1);   // round-to-nearest-even
  return (unsigned short)(u >> 16);
}

static __device__ __forceinline__ unsigned int pkbf(float a, float b) {
  unsigned short x = __builtin_bit_cast(unsigned short, (__bf16)a);
  unsigned short y = __builtin_bit_cast(unsigned short, (__bf16)b);
  return (unsigned int)x | ((unsigned int)y << 16);
}

static __device__ __forceinline__ f32x4 mfma16(s16x8 a, s16x8 b, f32x4 c) {
  return __builtin_amdgcn_mfma_f32_16x16x32_bf16(
      __builtin_bit_cast(bf16x8, a), __builtin_bit_cast(bf16x8, b), c, 0, 0, 0);
}

static __device__ __forceinline__ f32x16 mfma32(s16x8 a, s16x8 b, f32x16 c) {
  return __builtin_amdgcn_mfma_f32_32x32x16_bf16(
      __builtin_bit_cast(bf16x8, a), __builtin_bit_cast(bf16x8, b), c, 0, 0, 0);
}

typedef const __attribute__((address_space(1))) void gvoid_t;
typedef __attribute__((address_space(3))) void svoid_t;

static __device__ __forceinline__ void gload_lds16(const void* g, void* l) {
  __builtin_amdgcn_global_load_lds((gvoid_t*)g, (svoid_t*)l, 16, 0, 0);
}

// ---------------- fp32 -> bf16 elementwise (x) ----------------
__global__ void cvt_bf16_kernel(const float* __restrict__ in,
                                unsigned short* __restrict__ out, int n4) {
  int i = blockIdx.x * blockDim.x + threadIdx.x;
  int stride = gridDim.x * blockDim.x;
  for (int idx = i; idx < n4; idx += stride) {
    float4 v = ((const float4*)in)[idx];
    ushort4 o;
    o.x = f2bf(v.x); o.y = f2bf(v.y); o.z = f2bf(v.z); o.w = f2bf(v.w);
    ((ushort4*)out)[idx] = o;
  }
}

// ------------- transpose+convert: f32 [R][C] -> bf16 [C][R] -------------
__global__ void transpose_cvt_kernel(const float* __restrict__ in,
                                     unsigned short* __restrict__ out,
                                     int R, int C) {
  __shared__ float tile[32][33];
  int c0 = blockIdx.x * 32, r0 = blockIdx.y * 32;
  int tx = threadIdx.x, ty = threadIdx.y;
#pragma unroll
  for (int i = 0; i < 4; ++i)
    tile[ty + i*8][tx] = in[(size_t)(r0 + ty + i*8) * C + c0 + tx];
  __syncthreads();
#pragma unroll
  for (int i = 0; i < 4; ++i)
    out[(size_t)(c0 + ty + i*8) * R + r0 + tx] = f2bf(tile[tx][ty + i*8]);
}

// ------------- transpose V: VT[b][d][s] = qkv[b*S+s][2176+d] -------------
__global__ void transpose_v_kernel(const unsigned short* __restrict__ qkv,
                                   unsigned short* __restrict__ VT) {
  __shared__ unsigned short tile[32][33];
  int s0 = blockIdx.x * 32, d0 = blockIdx.y * 32, b = blockIdx.z;
  int tx = threadIdx.x, ty = threadIdx.y;
#pragma unroll
  for (int i = 0; i < 4; ++i)
    tile[ty + i*8][tx] =
        qkv[(size_t)(b*SEQ + s0 + ty + i*8) * QKVC + (D_MODEL + DH) + d0 + tx];
  __syncthreads();
#pragma unroll
  for (int i = 0; i < 4; ++i)
    VT[(size_t)(b*DH + d0 + ty + i*8) * SEQ + s0 + tx] = tile[tx][ty + i*8];
}

// ------------- GEMM: C[M,N] = A[M,K](bf16) * BT[N,K]^T(bf16) + bias -------------
template<int OUT_F32>
__global__ __launch_bounds__(256, 2)
void gemm_bt_kernel(const unsigned short* __restrict__ A,
                    const unsigned short* __restrict__ BT,
                    const float* __restrict__ bias,
                    void* __restrict__ Cout,
                    int M, int N, int K) {
  __shared__ unsigned short Al[128*32];
  __shared__ unsigned short Bl[128*32];
  int tid = threadIdx.x;
  int lane = tid & 63, wave = tid >> 6;
  int m0 = blockIdx.y * 128, n0 = blockIdx.x * 128;
  int wr = wave >> 1, wc = wave & 1;
  int fr = lane & 15, fq = lane >> 4;
  f32x4 acc[4][4] = {};

  int c0 = wave * 2;
  int kcol = (lane & 3) * 8;
  int rsub = (lane >> 2);

  for (int k0 = 0; k0 < K; k0 += 32) {
#pragma unroll
    for (int i = 0; i < 2; ++i) {
      int c = c0 + i;
      int row = c*16 + rsub;
      gload_lds16(A  + (size_t)(m0 + row)*K + k0 + kcol, (char*)Al + c*1024);
      gload_lds16(BT + (size_t)(n0 + row)*K + k0 + kcol, (char*)Bl + c*1024);
    }
    __syncthreads();
    s16x8 af[4], bfr[4];
#pragma unroll
    for (int m = 0; m < 4; ++m)
      af[m] = *(const s16x8*)&Al[(wr*64 + m*16 + fr)*32 + fq*8];
#pragma unroll
    for (int n = 0; n < 4; ++n)
      bfr[n] = *(const s16x8*)&Bl[(wc*64 + n*16 + fr)*32 + fq*8];
#pragma unroll
    for (int m = 0; m < 4; ++m)
#pragma unroll
      for (int n = 0; n < 4; ++n)
        acc[m][n] = mfma16(af[m], bfr[n], acc[m][n]);
    __syncthreads();
  }

#pragma unroll
  for (int n = 0; n < 4; ++n) {
    int col = n0 + wc*64 + n*16 + fr;
    float bv = bias[col];
#pragma unroll
    for (int m = 0; m < 4; ++m) {
      int rowb = m0 + wr*64 + m*16 + fq*4;
#pragma unroll
      for (int j = 0; j < 4; ++j) {
        float v = acc[m][n][j] + bv;
        if (OUT_F32) ((float*)Cout)[(size_t)(rowb + j)*N + col] = v;
        else ((unsigned short*)Cout)[(size_t)(rowb + j)*N + col] = f2bf(v);
      }
    }
  }
}

// ------------- causal MQA attention: uniform split-kv blocks -------------
// 256 blocks (1/CU), 512 threads = 8 waves = 2 groups of 4 (one head each).
// Block u: b = u>>7, hg = (u>>5)&3, x = u&31; qt_A = 63-x (long), qt_B = x.
// nkbA + nkbB = 33 for all x. Group 0: qt_A kv-blocks [0,17).
// Group 1: qt_B fully (nkbB blocks), then qt_A kv-blocks [17, nkbA) (16 total).
// Every block: exactly 17/16 steps -> identical duration, 2 waves/SIMD
// throughout, zero tail. qt_A halves merged intra-block via LDS partials.
__global__ __launch_bounds__(512, 2)
void mqa_attn_kernel(const unsigned short* __restrict__ qkv,
                     const unsigned short* __restrict__ VT,
                     unsigned short* __restrict__ O) {
  __shared__ unsigned short Kst[2][2][64*128];   // [stream][buf] 64 KB
  __shared__ unsigned short Vst[2][2][128*64];   // [stream][buf] 64 KB
  int u = blockIdx.x;                   // 0..255
  int b = u >> 7;
  int hg = (u >> 5) & 3;
  int x = u & 31;
  int qtA = 63 - x, qtB = x;
  int nkbA = (qtA >> 1) + 1, nkbB = (qtB >> 1) + 1;   // sum = 33
  const int G1 = 17;
  bool hasPart = (nkbA > G1);

  int tid = threadIdx.x;                // 0..511
  int grp = tid >> 8;                   // group / stream
  int tg  = tid & 255;                  // thread within group
  int lane = tid & 63;
  int wid4 = (tid >> 6) & 3;            // wave within group = head idx
  int fr = lane & 31, hi = lane >> 5;
  int h = hg*4 + wid4;
  const float C = 0.12751688f;          // (1/sqrt(128)) * log2(e)

  // which tile does group g work on at step st? (block-uniform per group)
  auto tile_desc = [&](int g, int st, int& qt, int& kb) -> bool {
    if (g == 0) { qt = qtA; kb = st; return st < G1; }
    if (st < nkbB) { qt = qtB; kb = st; return true; }
    int k2 = G1 + (st - nkbB);
    qt = qtA; kb = k2;
    return k2 < nkbA;
  };

#define STAGE_G(kv0_, Kp_, Vp_) do {                                        \
    _Pragma("unroll")                                                       \
    for (int i_ = 0; i_ < 4; ++i_) {                                        \
      int idx_ = i_*256 + tg;                                               \
      int r_ = idx_ >> 4, c_ = idx_ & 15;                                   \
      gload_lds16(qkv + (size_t)(b*SEQ + (kv0_) + r_)*QKVC + D_MODEL        \
                      + ((c_ ^ (r_ & 15)) * 8),                             \
                  (char*)(Kp_) + (size_t)idx_*16);                          \
      int d_ = idx_ >> 3, c2_ = idx_ & 7;                                   \
      gload_lds16(VT + (size_t)(b*DH + d_)*SEQ + (kv0_) + ((c2_^(d_&7))*8), \
                  (char*)(Vp_) + (size_t)idx_*16);                          \
    }                                                                       \
  } while (0)

  s16x8 qf[8];
  f32x16 oacc[4];
  float m_r, l_r;

  auto load_q = [&](int qt_) {
    const unsigned short* qb =
        qkv + (size_t)(b*SEQ + qt_*32 + fr)*QKVC + h*DH + hi*8;
#pragma unroll
    for (int s = 0; s < 8; ++s) qf[s] = *(const s16x8*)(qb + s*16);
  };
  auto reset_state = [&]() {
#pragma unroll
    for (int n2 = 0; n2 < 4; ++n2)
#pragma unroll
      for (int e = 0; e < 16; ++e) oacc[n2][e] = 0.f;
    m_r = -1.0e30f; l_r = 0.f;
  };

  auto do_tile = [&](const unsigned short* Kb, const unsigned short* Vb,
                     int q0, int kv0) {
    // QK^T (swapped): sfr[t] = S^T tile, D[row=kv][col=q]
    f32x16 sfr[2] = {};
    __builtin_amdgcn_s_setprio(1);
#pragma unroll
    for (int t = 0; t < 2; ++t) {
      int row = t*32 + fr;
#pragma unroll
      for (int s = 0; s < 8; ++s) {
        int cc = (s*2 + hi) ^ (fr & 15);
        s16x8 kf = *(const s16x8*)&Kb[row*128 + cc*8];
        sfr[t] = mfma32(kf, qf[s], sfr[t]);
      }
    }
    __builtin_amdgcn_s_setprio(0);

    // causal mask (raw-score domain) when tile crosses the diagonal
    if (kv0 + 63 > q0) {
      int q = q0 + fr;
#pragma unroll
      for (int t = 0; t < 2; ++t)
#pragma unroll
        for (int r = 0; r < 16; ++r) {
          int kv = kv0 + t*32 + (r & 3) + 8*(r >> 2) + 4*hi;
          if (kv > q) sfr[t][r] = -1.0e30f;
        }
    }

    // online softmax (folded scale*log2e, tree reductions, defer-max)
    float mx[8];
#pragma unroll
    for (int r = 0; r < 8; ++r)
      mx[r] = fmaxf(fmaxf(sfr[0][r], sfr[0][r+8]),
                    fmaxf(sfr[1][r], sfr[1][r+8]));
    float pm = fmaxf(fmaxf(fmaxf(mx[0], mx[4]), fmaxf(mx[1], mx[5])),
                     fmaxf(fmaxf(mx[2], mx[6]), fmaxf(mx[3], mx[7])));
    pm = fmaxf(pm, __shfl_xor(pm, 32));

    bool stable = __all(pm - m_r <= 90.0f) != 0;
    float fac = 1.0f;
    if (!stable) {
      float mnew = fmaxf(m_r, pm);
      fac = exp2f((m_r - mnew) * C);
      m_r = mnew;
    }
    float mC = m_r * C;
#pragma unroll
    for (int t = 0; t < 2; ++t)
#pragma unroll
      for (int r = 0; r < 16; ++r)
        sfr[t][r] = exp2f(__builtin_fmaf(sfr[t][r], C, -mC));

    float sm[8];
#pragma unroll
    for (int r = 0; r < 8; ++r)
      sm[r] = (sfr[0][r] + sfr[0][r+8]) + (sfr[1][r] + sfr[1][r+8]);
    float rs = ((sm[0]+sm[1]) + (sm[2]+sm[3]))
             + ((sm[4]+sm[5]) + (sm[6]+sm[7]));
    rs += __shfl_xor(rs, 32);
    l_r = l_r * fac + rs;

    if (!stable) {
#pragma unroll
      for (int r = 0; r < 16; ++r) {
        int src = (r & 3) + 8*(r >> 2) + 4*hi;
        float fv = __shfl(fac, src);
#pragma unroll
        for (int n2 = 0; n2 < 4; ++n2) oacc[n2][r] *= fv;
      }
    }

    // P -> A-fragments in-register (pack + shfl_xor 32) + PV
#pragma unroll
    for (int t = 0; t < 2; ++t) {
      s16x8 pa[2];
#pragma unroll
      for (int ks = 0; ks < 2; ++ks) {
        unsigned int X0 = pkbf(sfr[t][8*ks+0], sfr[t][8*ks+1]);
        unsigned int X1 = pkbf(sfr[t][8*ks+2], sfr[t][8*ks+3]);
        unsigned int Y0 = pkbf(sfr[t][8*ks+4], sfr[t][8*ks+5]);
        unsigned int Y1 = pkbf(sfr[t][8*ks+6], sfr[t][8*ks+7]);
        unsigned int s0 = __shfl_xor(hi ? X0 : Y0, 32);
        unsigned int s1 = __shfl_xor(hi ? X1 : Y1, 32);
        u32x4 pw;
        pw[0] = hi ? s0 : X0;
        pw[1] = hi ? s1 : X1;
        pw[2] = hi ? Y0 : s0;
        pw[3] = hi ? Y1 : s1;
        pa[ks] = __builtin_bit_cast(s16x8, pw);
      }
      __builtin_amdgcn_s_setprio(1);
#pragma unroll
      for (int n2 = 0; n2 < 4; ++n2) {
        int d = n2*32 + fr;
#pragma unroll
        for (int ks = 0; ks < 2; ++ks) {
          int cc = (t*4 + ks*2 + hi) ^ (d & 7);
          s16x8 vf = *(const s16x8*)&Vb[d*64 + cc*8];
          oacc[n2] = mfma32(pa[ks], vf, oacc[n2]);
        }
      }
      __builtin_amdgcn_s_setprio(0);
    }
  };

  auto do_epilogue = [&](int qt_) {
    float invl = 1.0f / l_r;
#pragma unroll
    for (int r = 0; r < 16; ++r) {
      int qrow = (r & 3) + 8*(r >> 2) + 4*hi;
      float iv = __shfl(invl, qrow);
      size_t rowoff = (size_t)(b*SEQ + qt_*32 + qrow)*D_MODEL + h*DH;
#pragma unroll
      for (int n2 = 0; n2 < 4; ++n2)
        O[rowoff + n2*32 + fr] = f2bf(oacc[n2][r] * iv);
    }
  };

  // ---- init ----
  load_q(grp ? qtB : qtA);
  reset_state();

  // ---- prologue: stage T(0) for my stream ----
  {
    int qts, kbs;
    tile_desc(grp, 0, qts, kbs);
    STAGE_G(kbs*64, &Kst[grp][0][0], &Vst[grp][0][0]);
  }
  __syncthreads();

  // ---- main loop: 17 lockstep steps ----
  for (int st = 0; st < G1; ++st) {
    int qtn, kbn;
    if (tile_desc(grp, st + 1, qtn, kbn))
      STAGE_G(kbn*64, &Kst[grp][(st+1)&1][0], &Vst[grp][(st+1)&1][0]);

    int qtc, kbc;
    if (tile_desc(grp, st, qtc, kbc)) {
      do_tile(&Kst[grp][st&1][0], &Vst[grp][st&1][0], qtc*32, kbc*64);
      if (grp == 1 && st == nkbB - 1) {
        do_epilogue(qtB);       // qt_B complete -> write it out
        load_q(qtA);            // switch to qt_A upper kv range
        reset_state();
      }
    }
    __syncthreads();
  }

  // ---- merge qt_A halves ----
  if (grp == 1 && hasPart) {
    float* Dls = (float*)&Kst[0][0][0];     // 16K floats = 64 KB
    float* Mls = (float*)&Vst[0][0][0];
#pragma unroll
    for (int r = 0; r < 16; ++r) {
      int q = (r & 3) + 8*(r >> 2) + 4*hi;
#pragma unroll
      for (int n2 = 0; n2 < 4; ++n2)
        Dls[(wid4*32 + q)*128 + n2*32 + fr] = oacc[n2][r];
    }
    if (hi == 0) {
      Mls[wid4*32 + fr] = m_r;
      Mls[128 + wid4*32 + fr] = l_r;
    }
  }
  __syncthreads();

  if (grp == 0) {
    if (hasPart) {
      const float* Dls = (const float*)&Kst[0][0][0];
      const float* Mls = (const float*)&Vst[0][0][0];
      float m2 = Mls[wid4*32 + fr], l2 = Mls[128 + wid4*32 + fr];
      float mm = fmaxf(m_r, m2);
      float fA = exp2f((m_r - mm) * C);
      float fB = exp2f((m2 - mm) * C);
      float inv = 1.0f / (fA*l_r + fB*l2);
#pragma unroll
      for (int r = 0; r < 16; ++r) {
        int q = (r & 3) + 8*(r >> 2) + 4*hi;
        float fAs = __shfl(fA, q), fBs = __shfl(fB, q), invs = __shfl(inv, q);
        size_t rowoff = (size_t)(b*SEQ + qtA*32 + q)*D_MODEL + h*DH;
#pragma unroll
        for (int n2 = 0; n2 < 4; ++n2) {
          float o2 = Dls[(wid4*32 + q)*128 + n2*32 + fr];
          O[rowoff + n2*32 + fr] = f2bf((fAs*oacc[n2][r] + fBs*o2) * invs);
        }
      }
    } else {
      do_epilogue(qtA);
    }
  }
#undef STAGE_G
}

extern "C" void kernel_launch(void* const* d_in, const int* in_sizes, int n_in,
                              void* d_out, int out_size, void* d_ws, size_t ws_size,
                              hipStream_t stream) {
  const float* x     = (const float*)d_in[0];
  const float* W_qkv = (const float*)d_in[1];
  const float* b_qkv = (const float*)d_in[2];
  const float* W_out = (const float*)d_in[3];
  const float* b_out = (const float*)d_in[4];
  float* out = (float*)d_out;

  unsigned short* x_bf = (unsigned short*)d_ws;
  unsigned short* WqT  = x_bf + (size_t)MROWS * D_MODEL;
  unsigned short* WoT  = WqT  + (size_t)QKVC * D_MODEL;
  unsigned short* qkvb = WoT  + (size_t)D_MODEL * D_MODEL;
  unsigned short* VTb  = qkvb + (size_t)MROWS * QKVC;
  unsigned short* Ob   = VTb  + (size_t)BATCH * DH * SEQ;

  dim3 tb(32, 8);
  cvt_bf16_kernel<<<2048, 256, 0, stream>>>(x, x_bf, (MROWS * D_MODEL) / 4);
  transpose_cvt_kernel<<<dim3(QKVC/32, D_MODEL/32), tb, 0, stream>>>(W_qkv, WqT, D_MODEL, QKVC);
  transpose_cvt_kernel<<<dim3(D_MODEL/32, D_MODEL/32), tb, 0, stream>>>(W_out, WoT, D_MODEL, D_MODEL);

  gemm_bt_kernel<0><<<dim3(QKVC/128, MROWS/128), 256, 0, stream>>>(
      x_bf, WqT, b_qkv, qkvb, MROWS, QKVC, D_MODEL);

  transpose_v_kernel<<<dim3(SEQ/32, DH/32, BATCH), tb, 0, stream>>>(qkvb, VTb);

  mqa_attn_kernel<<<dim3(256), 512, 0, stream>>>(qkvb, VTb, Ob);

  gemm_bt_kernel<1><<<dim3(D_MODEL/128, MROWS/128), 256, 0, stream>>>(
      Ob, WoT, b_out, out, MROWS, D_MODEL, D_MODEL);
}